// Round 2
// baseline (2295.671 us; speedup 1.0000x reference)
//
#include <hip/hip_runtime.h>

#define MM 200000      // messages
#define AA 100000      // atoms
#define KA 6
#define KB 5
#define NATOM 120
#define NBOND 4
#define NC (NATOM*NBOND)   // 480 combos
#define HH 256

typedef unsigned short ushort_t;
typedef __attribute__((ext_vector_type(8))) short bf16x8;
typedef __attribute__((ext_vector_type(4))) float f32x4;

// canonical bf16 weight arena offsets (ushort elements)
#define OFF_Ea   0
#define OFF_Eb   30720
#define OFF_Wz   31744
#define OFF_Wzb  228352
#define OFF_Wr   228608
#define OFF_Ur   359680
#define OFF_Urb  425216
#define OFF_Wh   425472
#define OFF_Whb  622080
#define OFF_O1   622336
#define OFF_O1b  753408
#define OFF_O2   753664
#define OFF_O2b  819200
#define W_TOTAL  819456

// ---------------- static device state ----------------
__device__ ushort_t g_h [MM*HH];   // h,   bf16
__device__ ushort_t g_uh[MM*HH];   // h @ Ur^T, bf16
__device__ ushort_t g_sh[MM*HH];   // sum_h, bf16
__device__ ushort_t g_sg[MM*HH];   // sum_gated, bf16
__device__ float    g_tr[NC*HH];   // x@Wr^T + Ur_b   per combo
__device__ float    g_tz[NC*HH];   // x-part of z preact + Wz_b
__device__ float    g_th[NC*HH];   // x-part of h preact + Wh_b
__device__ float    g_to1[NATOM*HH]; // hnode-part of O1 preact + O1_b
__device__ int      g_cidx[MM];
__device__ ushort_t c_w[W_TOTAL];  // canonical bf16 weights
__device__ int      g_isf32;       // 1 if float inputs are f32, 0 if bf16

// ---------------- helpers ----------------
__device__ inline float bf2f(ushort_t u){ return __uint_as_float(((unsigned)u)<<16); }
__device__ inline ushort_t f2bf(float f){
  unsigned u = __float_as_uint(f);
  unsigned r = (u + 0x7FFFu + ((u>>16)&1u)) >> 16;
  return (ushort_t)r;
}
__device__ inline float sigm(float x){ return 1.0f/(1.0f + __expf(-x)); }
__device__ inline float tanh_f(float x){
  float ax = fabsf(x);
  float e = __expf(-2.0f*ax);
  float t = (1.0f - e)/(1.0f + e);
  return copysignf(t, x);
}
// LDS swizzle: ushort-index for a [64][256] bf16 tile, XOR bits 3..5 with row&7
__device__ inline int sidx(int row, int col){ return row*256 + (col ^ ((row&7)<<3)); }

__device__ inline bf16x8 ldsA(const ushort_t* tile, int m0, int lane, int k0){
  int row = m0 + (lane & 15);
  int col = k0 + 8*(lane>>4);
  return *(const bf16x8*)(tile + sidx(row, col));
}
__device__ inline bf16x8 ldgB(const ushort_t* W, int ldw, int koff, int n0, int lane, int k0){
  int n = n0 + (lane & 15);
  int k = koff + k0 + 8*(lane>>4);
  return *(const bf16x8*)(W + n*ldw + k);
}
__device__ inline f32x4 mfma16(bf16x8 a, bf16x8 b, f32x4 c){
  return __builtin_amdgcn_mfma_f32_16x16x32_bf16(a, b, c, 0, 0, 0);
}

// ---------------- K-detect: is the float data f32 or bf16? ------------------
__global__ __launch_bounds__(256) void k_detect(const ushort_t* Ea_raw){
  __shared__ int sbad;
  if (threadIdx.x == 0) sbad = 0;
  __syncthreads();
  // sample even ushort indices; if storage is f32 these are mantissa-low halves
  // with uniformly random exponent fields -> wild magnitudes.
  float v = bf2f(Ea_raw[2*threadIdx.x]);
  float av = fabsf(v);
  int bad = (av > 1e4f) || (av != 0.0f && av < 1e-30f);
  atomicAdd(&sbad, bad);
  __syncthreads();
  if (threadIdx.x == 0) g_isf32 = (sbad > 64) ? 1 : 0;
}

// ---------------- K-convert: build canonical bf16 arena ---------------------
__global__ __launch_bounds__(256) void k_convert(
    const void* Ea, const void* Eb, const void* Wz, const void* Wzb,
    const void* Wr, const void* Ur, const void* Urb, const void* Wh,
    const void* Whb, const void* O1, const void* O1b, const void* O2,
    const void* O2b)
{
  int idx = blockIdx.x*256 + threadIdx.x;
  if (idx >= W_TOTAL) return;
  const void* src; int j;
  if      (idx < OFF_Eb)  { src = Ea;  j = idx - OFF_Ea; }
  else if (idx < OFF_Wz)  { src = Eb;  j = idx - OFF_Eb; }
  else if (idx < OFF_Wzb) { src = Wz;  j = idx - OFF_Wz; }
  else if (idx < OFF_Wr)  { src = Wzb; j = idx - OFF_Wzb; }
  else if (idx < OFF_Ur)  { src = Wr;  j = idx - OFF_Wr; }
  else if (idx < OFF_Urb) { src = Ur;  j = idx - OFF_Ur; }
  else if (idx < OFF_Wh)  { src = Urb; j = idx - OFF_Urb; }
  else if (idx < OFF_Whb) { src = Wh;  j = idx - OFF_Wh; }
  else if (idx < OFF_O1)  { src = Whb; j = idx - OFF_Whb; }
  else if (idx < OFF_O1b) { src = O1;  j = idx - OFF_O1; }
  else if (idx < OFF_O2)  { src = O1b; j = idx - OFF_O1b; }
  else if (idx < OFF_O2b) { src = O2;  j = idx - OFF_O2; }
  else                    { src = O2b; j = idx - OFF_O2b; }
  ushort_t v;
  if (g_isf32) v = f2bf(((const float*)src)[j]);
  else         v = ((const ushort_t*)src)[j];
  c_w[idx] = v;
}

// ---------------- K0: build tables (480 combos x 3 + 120 atom rows) --------
__global__ __launch_bounds__(256) void k_tables()
{
  const ushort_t* Ea  = c_w + OFF_Ea;
  const ushort_t* Eb  = c_w + OFF_Eb;
  int b = blockIdx.x, o = threadIdx.x;
  if (b < 3*NC) {
    int t = b / NC, c = b % NC, a = c >> 2, bd = c & 3;
    const ushort_t* W; const ushort_t* bias; int ldw;
    if (t == 0)      { W = c_w + OFF_Wr; bias = c_w + OFF_Urb; ldw = 512; }
    else if (t == 1) { W = c_w + OFF_Wz; bias = c_w + OFF_Wzb; ldw = 768; }
    else             { W = c_w + OFF_Wh; bias = c_w + OFF_Whb; ldw = 768; }
    float acc = bf2f(bias[o]);
    const ushort_t* wrow = W + o*ldw;
    for (int d = 0; d < 256; d++) acc += bf2f(Ea[a*256+d]) * bf2f(wrow[d]);
    for (int d = 0; d < 256; d++) acc += bf2f(Eb[bd*256+d]) * bf2f(wrow[256+d]);
    float* T = (t==0) ? g_tr : (t==1) ? g_tz : g_th;
    T[c*256 + o] = acc;
  } else {
    int a = b - 3*NC;
    float acc = bf2f(c_w[OFF_O1b + o]);
    const ushort_t* wrow = c_w + OFF_O1 + o*512;
    for (int d = 0; d < 256; d++) acc += bf2f(Ea[a*256+d]) * bf2f(wrow[d]);
    g_to1[a*256 + o] = acc;
  }
}

// ---------------- K1: combo index per message ------------------------------
__global__ __launch_bounds__(256) void k_cidx(const int* fnode, const int* fsrc, const int* fbond){
  int m = blockIdx.x*256 + threadIdx.x;
  if (m >= MM) return;
  g_cidx[m] = fnode[fsrc[m]]*4 + fbond[m];
}

// ---------------- K2: iteration 0 (h=0 -> table only) + Uh GEMM ------------
__global__ __launch_bounds__(256) void k_iter0(){
  __shared__ __align__(16) ushort_t sT[64*256];
  const ushort_t* Ur = c_w + OFF_Ur;
  int base = blockIdx.x * 64;
  int t = threadIdx.x;
  {
    int row = t >> 2, cb = (t & 3) * 64;
    int m = base + row;
    int c = g_cidx[m];
    float msk = (m != 0) ? 1.0f : 0.0f;
    #pragma unroll
    for (int e = 0; e < 64; e += 4){
      int col = cb + e;
      float4 tz = *(const float4*)(g_tz + c*256 + col);
      float4 th = *(const float4*)(g_th + c*256 + col);
      ushort_t h0 = f2bf(msk * sigm(tz.x) * tanh_f(th.x));
      ushort_t h1 = f2bf(msk * sigm(tz.y) * tanh_f(th.y));
      ushort_t h2 = f2bf(msk * sigm(tz.z) * tanh_f(th.z));
      ushort_t h3 = f2bf(msk * sigm(tz.w) * tanh_f(th.w));
      ushort4 hv = make_ushort4(h0, h1, h2, h3);
      *(ushort4*)(g_h + m*256 + col) = hv;
      *(ushort4*)(sT + sidx(row, col)) = hv;
    }
  }
  __syncthreads();
  int w = t >> 6, lane = t & 63, n0w = w*64, ln = lane & 15, hi = lane >> 4;
  f32x4 acc[4][4];
  #pragma unroll
  for (int i=0;i<4;i++)
    #pragma unroll
    for (int j=0;j<4;j++) acc[i][j] = (f32x4){0.f,0.f,0.f,0.f};
  for (int kt = 0; kt < 8; kt++){
    int k0 = kt*32;
    bf16x8 aF[4], bF[4];
    #pragma unroll
    for (int i=0;i<4;i++) aF[i] = ldsA(sT, i*16, lane, k0);
    #pragma unroll
    for (int i=0;i<4;i++) bF[i] = ldgB(Ur, 256, 0, n0w + i*16, lane, k0);
    #pragma unroll
    for (int mi=0;mi<4;mi++)
      #pragma unroll
      for (int ni=0;ni<4;ni++) acc[mi][ni] = mfma16(aF[mi], bF[ni], acc[mi][ni]);
  }
  #pragma unroll
  for (int mi=0;mi<4;mi++)
    #pragma unroll
    for (int ni=0;ni<4;ni++){
      int col = n0w + ni*16 + ln;
      #pragma unroll
      for (int r=0;r<4;r++){
        int rowg = base + mi*16 + hi*4 + r;
        g_uh[rowg*256 + col] = f2bf(acc[mi][ni][r]);
      }
    }
}

// ---------------- K3: gather sum_h & sum_gated over bgraph -----------------
__global__ __launch_bounds__(256) void k_gather(const int* bgraph){
  int w = threadIdx.x >> 6, lane = threadIdx.x & 63;
  int base = blockIdx.x * 32;
  for (int i = 0; i < 8; i++){
    int m = base + w*8 + i;
    int c = g_cidx[m];
    float4 tr = *(const float4*)(g_tr + c*256 + lane*4);
    float sh0=0,sh1=0,sh2=0,sh3=0, sg0=0,sg1=0,sg2=0,sg3=0;
    #pragma unroll
    for (int k = 0; k < KB; k++){
      int j = bgraph[m*KB + k];
      ushort4 hv = *(const ushort4*)(g_h  + j*256 + lane*4);
      ushort4 uv = *(const ushort4*)(g_uh + j*256 + lane*4);
      float h0=bf2f(hv.x), h1=bf2f(hv.y), h2=bf2f(hv.z), h3=bf2f(hv.w);
      float r0=sigm(tr.x+bf2f(uv.x)), r1=sigm(tr.y+bf2f(uv.y));
      float r2=sigm(tr.z+bf2f(uv.z)), r3=sigm(tr.w+bf2f(uv.w));
      sh0+=h0; sh1+=h1; sh2+=h2; sh3+=h3;
      sg0+=r0*h0; sg1+=r1*h1; sg2+=r2*h2; sg3+=r3*h3;
    }
    *(ushort4*)(g_sh + m*256 + lane*4) = make_ushort4(f2bf(sh0),f2bf(sh1),f2bf(sh2),f2bf(sh3));
    *(ushort4*)(g_sg + m*256 + lane*4) = make_ushort4(f2bf(sg0),f2bf(sg1),f2bf(sg2),f2bf(sg3));
  }
}

// ---------------- K4: GRU update (2 GEMMs + elementwise + Uh GEMM) ---------
__global__ __launch_bounds__(256) void k_update(){
  __shared__ __align__(16) ushort_t sA[64*256];  // sum_h tile
  __shared__ __align__(16) ushort_t sB[64*256];  // sum_gated tile -> later h_new tile
  const ushort_t* Wz = c_w + OFF_Wz;
  const ushort_t* Wh = c_w + OFF_Wh;
  const ushort_t* Ur = c_w + OFF_Ur;
  int base = blockIdx.x*64, t = threadIdx.x;
  #pragma unroll
  for (int p = 0; p < 8; p++){
    int flatu = p*2048 + t*8;
    int row = flatu >> 8, col = flatu & 255;
    *(bf16x8*)(sA + sidx(row,col)) = *(const bf16x8*)(g_sh + (base+row)*256 + col);
    *(bf16x8*)(sB + sidx(row,col)) = *(const bf16x8*)(g_sg + (base+row)*256 + col);
  }
  __syncthreads();
  int w = t>>6, lane = t&63, n0w = w*64, ln = lane&15, hi = lane>>4;
  f32x4 accz[4][4], acch[4][4];
  #pragma unroll
  for (int i=0;i<4;i++)
    #pragma unroll
    for (int j=0;j<4;j++){ accz[i][j]=(f32x4){0,0,0,0}; acch[i][j]=(f32x4){0,0,0,0}; }
  for (int kt = 0; kt < 8; kt++){
    int k0 = kt*32;
    bf16x8 aF[4], bF[4];
    #pragma unroll
    for (int i=0;i<4;i++) aF[i] = ldsA(sA, i*16, lane, k0);
    #pragma unroll
    for (int i=0;i<4;i++) bF[i] = ldgB(Wz, 768, 512, n0w + i*16, lane, k0);
    #pragma unroll
    for (int mi=0;mi<4;mi++)
      #pragma unroll
      for (int ni=0;ni<4;ni++) accz[mi][ni] = mfma16(aF[mi], bF[ni], accz[mi][ni]);
  }
  for (int kt = 0; kt < 8; kt++){
    int k0 = kt*32;
    bf16x8 aF[4], bF[4];
    #pragma unroll
    for (int i=0;i<4;i++) aF[i] = ldsA(sB, i*16, lane, k0);
    #pragma unroll
    for (int i=0;i<4;i++) bF[i] = ldgB(Wh, 768, 512, n0w + i*16, lane, k0);
    #pragma unroll
    for (int mi=0;mi<4;mi++)
      #pragma unroll
      for (int ni=0;ni<4;ni++) acch[mi][ni] = mfma16(aF[mi], bF[ni], acch[mi][ni]);
  }
  __syncthreads();   // all waves done reading sA/sB
  #pragma unroll
  for (int mi=0;mi<4;mi++)
    #pragma unroll
    for (int ni=0;ni<4;ni++){
      int col = n0w + ni*16 + ln;
      #pragma unroll
      for (int r=0;r<4;r++){
        int rowl = mi*16 + hi*4 + r;
        int rowg = base + rowl;
        int c = g_cidx[rowg];
        float shv = bf2f(sA[sidx(rowl, col)]);
        float z  = sigm(g_tz[c*256+col] + accz[mi][ni][r]);
        float ph = tanh_f(g_th[c*256+col] + acch[mi][ni][r]);
        float hn = (1.0f - z)*shv + z*ph;
        if (rowg == 0) hn = 0.f;
        ushort_t hb = f2bf(hn);
        g_h[rowg*256+col] = hb;
        sB[sidx(rowl,col)] = hb;
      }
    }
  __syncthreads();
  f32x4 accu[4][4];
  #pragma unroll
  for (int i=0;i<4;i++)
    #pragma unroll
    for (int j=0;j<4;j++) accu[i][j]=(f32x4){0,0,0,0};
  for (int kt = 0; kt < 8; kt++){
    int k0 = kt*32;
    bf16x8 aF[4], bF[4];
    #pragma unroll
    for (int i=0;i<4;i++) aF[i] = ldsA(sB, i*16, lane, k0);
    #pragma unroll
    for (int i=0;i<4;i++) bF[i] = ldgB(Ur, 256, 0, n0w + i*16, lane, k0);
    #pragma unroll
    for (int mi=0;mi<4;mi++)
      #pragma unroll
      for (int ni=0;ni<4;ni++) accu[mi][ni] = mfma16(aF[mi], bF[ni], accu[mi][ni]);
  }
  #pragma unroll
  for (int mi=0;mi<4;mi++)
    #pragma unroll
    for (int ni=0;ni<4;ni++){
      int col = n0w + ni*16 + ln;
      #pragma unroll
      for (int r=0;r<4;r++){
        int rowg = base + mi*16 + hi*4 + r;
        g_uh[rowg*256 + col] = f2bf(accu[mi][ni][r]);
      }
    }
}

// ---------------- K5: tail (agraph gather + O1 relu + O2) ------------------
__global__ __launch_bounds__(256) void k_tail(const int* agraph, const int* fnode,
                                              void* out_v){
  __shared__ __align__(16) ushort_t sT[64*256];
  const ushort_t* O1  = c_w + OFF_O1;
  const ushort_t* O2  = c_w + OFF_O2;
  const ushort_t* O2b = c_w + OFF_O2b;
  int base = blockIdx.x*64, t = threadIdx.x;
  int w = t>>6, lane = t&63;
  for (int i = 0; i < 16; i++){
    int rowl = w*16 + i;
    int a = base + rowl;
    float a0=0,a1=0,a2=0,a3=0;
    if (a < AA){
      #pragma unroll
      for (int k = 0; k < KA; k++){
        int j = agraph[a*KA + k];
        ushort4 hv = *(const ushort4*)(g_h + j*256 + lane*4);
        a0+=bf2f(hv.x); a1+=bf2f(hv.y); a2+=bf2f(hv.z); a3+=bf2f(hv.w);
      }
    }
    *(ushort4*)(sT + sidx(rowl, lane*4)) = make_ushort4(f2bf(a0),f2bf(a1),f2bf(a2),f2bf(a3));
  }
  __syncthreads();
  int n0w = w*64, ln = lane&15, hi = lane>>4;
  f32x4 acc[4][4];
  #pragma unroll
  for (int i=0;i<4;i++)
    #pragma unroll
    for (int j=0;j<4;j++) acc[i][j]=(f32x4){0,0,0,0};
  for (int kt = 0; kt < 8; kt++){
    int k0 = kt*32;
    bf16x8 aF[4], bF[4];
    #pragma unroll
    for (int i=0;i<4;i++) aF[i] = ldsA(sT, i*16, lane, k0);
    #pragma unroll
    for (int i=0;i<4;i++) bF[i] = ldgB(O1, 512, 256, n0w + i*16, lane, k0);
    #pragma unroll
    for (int mi=0;mi<4;mi++)
      #pragma unroll
      for (int ni=0;ni<4;ni++) acc[mi][ni] = mfma16(aF[mi], bF[ni], acc[mi][ni]);
  }
  __syncthreads();  // all waves done reading sT
  #pragma unroll
  for (int mi=0;mi<4;mi++)
    #pragma unroll
    for (int ni=0;ni<4;ni++){
      int col = n0w + ni*16 + ln;
      #pragma unroll
      for (int r=0;r<4;r++){
        int rowl = mi*16 + hi*4 + r;
        int a = base + rowl;
        int tt = (a < AA) ? fnode[a] : 0;
        float pre = g_to1[tt*256+col] + acc[mi][ni][r];
        sT[sidx(rowl,col)] = f2bf(fmaxf(pre, 0.f));
      }
    }
  __syncthreads();
  f32x4 acco[4][4];
  #pragma unroll
  for (int i=0;i<4;i++)
    #pragma unroll
    for (int j=0;j<4;j++) acco[i][j]=(f32x4){0,0,0,0};
  for (int kt = 0; kt < 8; kt++){
    int k0 = kt*32;
    bf16x8 aF[4], bF[4];
    #pragma unroll
    for (int i=0;i<4;i++) aF[i] = ldsA(sT, i*16, lane, k0);
    #pragma unroll
    for (int i=0;i<4;i++) bF[i] = ldgB(O2, 256, 0, n0w + i*16, lane, k0);
    #pragma unroll
    for (int mi=0;mi<4;mi++)
      #pragma unroll
      for (int ni=0;ni<4;ni++) acco[mi][ni] = mfma16(aF[mi], bF[ni], acco[mi][ni]);
  }
  int isf32 = g_isf32;
  #pragma unroll
  for (int mi=0;mi<4;mi++)
    #pragma unroll
    for (int ni=0;ni<4;ni++){
      int col = n0w + ni*16 + ln;
      float bias = bf2f(O2b[col]);
      #pragma unroll
      for (int r=0;r<4;r++){
        int rowg = base + mi*16 + hi*4 + r;
        if (rowg < AA){
          float v = acco[mi][ni][r] + bias;
          if (isf32) ((float*)out_v)[rowg*256 + col] = v;
          else       ((ushort_t*)out_v)[rowg*256 + col] = f2bf(v);
        }
      }
    }
}

// ---------------- launch ----------------------------------------------------
extern "C" void kernel_launch(void* const* d_in, const int* in_sizes, int n_in,
                              void* d_out, int out_size, void* d_ws, size_t ws_size,
                              hipStream_t stream) {
  const int* fnode = (const int*)d_in[13];
  const int* fsrc  = (const int*)d_in[14];
  const int* fbond = (const int*)d_in[15];
  const int* agraph = (const int*)d_in[16];
  const int* bgraph = (const int*)d_in[17];
  // depth is fixed at 4 by the problem setup

  k_detect<<<1, 256, 0, stream>>>((const ushort_t*)d_in[0]);
  k_convert<<<(W_TOTAL + 255)/256, 256, 0, stream>>>(
      d_in[0], d_in[1], d_in[2], d_in[3], d_in[4], d_in[5], d_in[6],
      d_in[7], d_in[8], d_in[9], d_in[10], d_in[11], d_in[12]);
  k_tables<<<3*NC + NATOM, 256, 0, stream>>>();
  k_cidx<<<(MM + 255)/256, 256, 0, stream>>>(fnode, fsrc, fbond);
  k_iter0<<<MM/64, 256, 0, stream>>>();
  for (int it = 1; it < 4; it++){
    k_gather<<<MM/32, 256, 0, stream>>>(bgraph);
    k_update<<<MM/64, 256, 0, stream>>>();
  }
  k_tail<<<(AA + 63)/64, 256, 0, stream>>>(agraph, fnode, (void*)d_out);
}

// Round 3
// 2026.977 us; speedup vs baseline: 1.1326x; 1.1326x over previous
//
#include <hip/hip_runtime.h>

#define MM 200000      // messages
#define AA 100000      // atoms
#define KA 6
#define KB 5
#define NATOM 120
#define NBOND 4
#define NC (NATOM*NBOND)   // 480 combos
#define HH 256
#define HU_LD 512          // interleaved row: [0..255]=h, [256..511]=uh

typedef unsigned short ushort_t;
typedef __attribute__((ext_vector_type(8))) short bf16x8;
typedef __attribute__((ext_vector_type(4))) float f32x4;

// canonical bf16 weight arena offsets (ushort elements)
#define OFF_Ea   0
#define OFF_Eb   30720
#define OFF_Wz   31744
#define OFF_Wzb  228352
#define OFF_Wr   228608
#define OFF_Ur   359680
#define OFF_Urb  425216
#define OFF_Wh   425472
#define OFF_Whb  622080
#define OFF_O1   622336
#define OFF_O1b  753408
#define OFF_O2   753664
#define OFF_O2b  819200
#define W_TOTAL  819456

// ---------------- static device state ----------------
__device__ ushort_t g_hu0[MM*HU_LD];  // ping
__device__ ushort_t g_hu1[MM*HU_LD];  // pong
__device__ float    g_tr[NC*HH];      // x@Wr^T + Ur_b   per combo
__device__ float    g_tz[NC*HH];      // x-part of z preact + Wz_b
__device__ float    g_th[NC*HH];      // x-part of h preact + Wh_b
__device__ float    g_to1[NATOM*HH];  // hnode-part of O1 preact + O1_b
__device__ int      g_cidx[MM];
__device__ ushort_t c_w[W_TOTAL];     // canonical bf16 weights
__device__ int      g_isf32;          // 1 if float inputs are f32

// ---------------- helpers ----------------
__device__ inline float bf2f(ushort_t u){ return __uint_as_float(((unsigned)u)<<16); }
__device__ inline ushort_t f2bf(float f){
  unsigned u = __float_as_uint(f);
  unsigned r = (u + 0x7FFFu + ((u>>16)&1u)) >> 16;
  return (ushort_t)r;
}
__device__ inline float sigm(float x){ return 1.0f/(1.0f + __expf(-x)); }
__device__ inline float tanh_f(float x){
  float ax = fabsf(x);
  float e = __expf(-2.0f*ax);
  float t = (1.0f - e)/(1.0f + e);
  return copysignf(t, x);
}
// LDS swizzle: ushort-index within a [rows][256] bf16 tile
__device__ inline int sidx(int row, int col){ return row*256 + (col ^ ((row&7)<<3)); }

__device__ inline bf16x8 ldsA(const ushort_t* tile, int m0, int lane, int k0){
  int row = m0 + (lane & 15);
  int col = k0 + 8*(lane>>4);
  return *(const bf16x8*)(tile + sidx(row, col));
}
__device__ inline bf16x8 ldgB(const ushort_t* W, int ldw, int koff, int n0, int lane, int k0){
  int n = n0 + (lane & 15);
  int k = koff + k0 + 8*(lane>>4);
  return *(const bf16x8*)(W + n*ldw + k);
}
__device__ inline f32x4 mfma16(bf16x8 a, bf16x8 b, f32x4 c){
  return __builtin_amdgcn_mfma_f32_16x16x32_bf16(a, b, c, 0, 0, 0);
}

// ---------------- K-detect: is the float data f32 or bf16? ------------------
__global__ __launch_bounds__(256) void k_detect(const ushort_t* Ea_raw){
  __shared__ int sbad;
  if (threadIdx.x == 0) sbad = 0;
  __syncthreads();
  float v = bf2f(Ea_raw[2*threadIdx.x]);
  float av = fabsf(v);
  int bad = (av > 1e4f) || (av != 0.0f && av < 1e-30f);
  atomicAdd(&sbad, bad);
  __syncthreads();
  if (threadIdx.x == 0) g_isf32 = (sbad > 64) ? 1 : 0;
}

// ---------------- K-convert: build canonical bf16 arena ---------------------
__global__ __launch_bounds__(256) void k_convert(
    const void* Ea, const void* Eb, const void* Wz, const void* Wzb,
    const void* Wr, const void* Ur, const void* Urb, const void* Wh,
    const void* Whb, const void* O1, const void* O1b, const void* O2,
    const void* O2b)
{
  int idx = blockIdx.x*256 + threadIdx.x;
  if (idx >= W_TOTAL) return;
  const void* src; int j;
  if      (idx < OFF_Eb)  { src = Ea;  j = idx - OFF_Ea; }
  else if (idx < OFF_Wz)  { src = Eb;  j = idx - OFF_Eb; }
  else if (idx < OFF_Wzb) { src = Wz;  j = idx - OFF_Wz; }
  else if (idx < OFF_Wr)  { src = Wzb; j = idx - OFF_Wzb; }
  else if (idx < OFF_Ur)  { src = Wr;  j = idx - OFF_Wr; }
  else if (idx < OFF_Urb) { src = Ur;  j = idx - OFF_Ur; }
  else if (idx < OFF_Wh)  { src = Urb; j = idx - OFF_Urb; }
  else if (idx < OFF_Whb) { src = Wh;  j = idx - OFF_Wh; }
  else if (idx < OFF_O1)  { src = Whb; j = idx - OFF_Whb; }
  else if (idx < OFF_O1b) { src = O1;  j = idx - OFF_O1; }
  else if (idx < OFF_O2)  { src = O1b; j = idx - OFF_O1b; }
  else if (idx < OFF_O2b) { src = O2;  j = idx - OFF_O2; }
  else                    { src = O2b; j = idx - OFF_O2b; }
  ushort_t v;
  if (g_isf32) v = f2bf(((const float*)src)[j]);
  else         v = ((const ushort_t*)src)[j];
  c_w[idx] = v;
}

// ---------------- K0: build tables -----------------------------------------
__global__ __launch_bounds__(256) void k_tables()
{
  const ushort_t* Ea  = c_w + OFF_Ea;
  const ushort_t* Eb  = c_w + OFF_Eb;
  int b = blockIdx.x, o = threadIdx.x;
  if (b < 3*NC) {
    int t = b / NC, c = b % NC, a = c >> 2, bd = c & 3;
    const ushort_t* W; const ushort_t* bias; int ldw;
    if (t == 0)      { W = c_w + OFF_Wr; bias = c_w + OFF_Urb; ldw = 512; }
    else if (t == 1) { W = c_w + OFF_Wz; bias = c_w + OFF_Wzb; ldw = 768; }
    else             { W = c_w + OFF_Wh; bias = c_w + OFF_Whb; ldw = 768; }
    float acc = bf2f(bias[o]);
    const ushort_t* wrow = W + o*ldw;
    for (int d = 0; d < 256; d++) acc += bf2f(Ea[a*256+d]) * bf2f(wrow[d]);
    for (int d = 0; d < 256; d++) acc += bf2f(Eb[bd*256+d]) * bf2f(wrow[256+d]);
    float* T = (t==0) ? g_tr : (t==1) ? g_tz : g_th;
    T[c*256 + o] = acc;
  } else {
    int a = b - 3*NC;
    float acc = bf2f(c_w[OFF_O1b + o]);
    const ushort_t* wrow = c_w + OFF_O1 + o*512;
    for (int d = 0; d < 256; d++) acc += bf2f(Ea[a*256+d]) * bf2f(wrow[d]);
    g_to1[a*256 + o] = acc;
  }
}

// ---------------- K1: combo index per message ------------------------------
__global__ __launch_bounds__(256) void k_cidx(const int* fnode, const int* fsrc, const int* fbond){
  int m = blockIdx.x*256 + threadIdx.x;
  if (m >= MM) return;
  g_cidx[m] = fnode[fsrc[m]]*4 + fbond[m];
}

// ---------------- K2: iteration 0 (h=0 -> table only) + Uh GEMM ------------
__global__ __launch_bounds__(256) void k_iter0(){
  __shared__ __align__(16) ushort_t sT[64*256];
  const ushort_t* Ur = c_w + OFF_Ur;
  ushort_t* hu = g_hu0;
  int base = blockIdx.x * 64;
  int t = threadIdx.x;
  {
    int row = t >> 2, cb = (t & 3) * 64;
    int m = base + row;
    int c = g_cidx[m];
    float msk = (m != 0) ? 1.0f : 0.0f;
    #pragma unroll
    for (int e = 0; e < 64; e += 4){
      int col = cb + e;
      float4 tz = *(const float4*)(g_tz + c*256 + col);
      float4 th = *(const float4*)(g_th + c*256 + col);
      ushort_t h0 = f2bf(msk * sigm(tz.x) * tanh_f(th.x));
      ushort_t h1 = f2bf(msk * sigm(tz.y) * tanh_f(th.y));
      ushort_t h2 = f2bf(msk * sigm(tz.z) * tanh_f(th.z));
      ushort_t h3 = f2bf(msk * sigm(tz.w) * tanh_f(th.w));
      ushort4 hv = make_ushort4(h0, h1, h2, h3);
      *(ushort4*)(hu + (size_t)m*HU_LD + col) = hv;
      *(ushort4*)(sT + sidx(row, col)) = hv;
    }
  }
  __syncthreads();
  int w = t >> 6, lane = t & 63, n0w = w*64, ln = lane & 15, hi = lane >> 4;
  f32x4 acc[4][4];
  #pragma unroll
  for (int i=0;i<4;i++)
    #pragma unroll
    for (int j=0;j<4;j++) acc[i][j] = (f32x4){0.f,0.f,0.f,0.f};
  for (int kt = 0; kt < 8; kt++){
    int k0 = kt*32;
    bf16x8 aF[4], bF[4];
    #pragma unroll
    for (int i=0;i<4;i++) aF[i] = ldsA(sT, i*16, lane, k0);
    #pragma unroll
    for (int i=0;i<4;i++) bF[i] = ldgB(Ur, 256, 0, n0w + i*16, lane, k0);
    #pragma unroll
    for (int mi=0;mi<4;mi++)
      #pragma unroll
      for (int ni=0;ni<4;ni++) acc[mi][ni] = mfma16(aF[mi], bF[ni], acc[mi][ni]);
  }
  #pragma unroll
  for (int mi=0;mi<4;mi++)
    #pragma unroll
    for (int ni=0;ni<4;ni++){
      int col = n0w + ni*16 + ln;
      #pragma unroll
      for (int r=0;r<4;r++){
        int rowg = base + mi*16 + hi*4 + r;
        hu[(size_t)rowg*HU_LD + 256 + col] = f2bf(acc[mi][ni][r]);
      }
    }
}

// ---------------- K-fused: gather + GRU update + Uh GEMM (ping-pong) -------
__global__ __launch_bounds__(256) void k_fused(const int* __restrict__ bgraph, int rd, int last){
  __shared__ __align__(16) ushort_t sA[32*256];  // sum_h
  __shared__ __align__(16) ushort_t sB[32*256];  // sum_gated -> h_new
  __shared__ int sC[32];
  const ushort_t* __restrict__ hup = rd ? g_hu1 : g_hu0;
  ushort_t* hun = rd ? g_hu0 : g_hu1;
  const ushort_t* Wz = c_w + OFF_Wz;
  const ushort_t* Wh = c_w + OFF_Wh;
  const ushort_t* Ur = c_w + OFF_Ur;
  int base = blockIdx.x*32, t = threadIdx.x;
  int w = t>>6, lane = t&63;

  // ---- gather phase: 8 rows per wave, each lane covers 4 cols ----
  #pragma unroll
  for (int i = 0; i < 8; i++){
    int row = w*8 + i;
    int m = base + row;
    int c = g_cidx[m];
    if (lane == 0) sC[row] = c;
    float4 tr = *(const float4*)(g_tr + c*256 + lane*4);
    int js[KB];
    #pragma unroll
    for (int k = 0; k < KB; k++) js[k] = bgraph[m*KB + k];
    float sh0=0,sh1=0,sh2=0,sh3=0, sg0=0,sg1=0,sg2=0,sg3=0;
    #pragma unroll
    for (int k = 0; k < KB; k++){
      const ushort_t* rp = hup + (size_t)js[k]*HU_LD;
      ushort4 hv = *(const ushort4*)(rp + lane*4);
      ushort4 uv = *(const ushort4*)(rp + 256 + lane*4);
      float h0=bf2f(hv.x), h1=bf2f(hv.y), h2=bf2f(hv.z), h3=bf2f(hv.w);
      float r0=sigm(tr.x+bf2f(uv.x)), r1=sigm(tr.y+bf2f(uv.y));
      float r2=sigm(tr.z+bf2f(uv.z)), r3=sigm(tr.w+bf2f(uv.w));
      sh0+=h0; sh1+=h1; sh2+=h2; sh3+=h3;
      sg0+=r0*h0; sg1+=r1*h1; sg2+=r2*h2; sg3+=r3*h3;
    }
    *(ushort4*)(sA + sidx(row, lane*4)) = make_ushort4(f2bf(sh0),f2bf(sh1),f2bf(sh2),f2bf(sh3));
    *(ushort4*)(sB + sidx(row, lane*4)) = make_ushort4(f2bf(sg0),f2bf(sg1),f2bf(sg2),f2bf(sg3));
  }
  __syncthreads();

  // ---- GEMM phase: z (sA x Wz) and pre_h (sB x Wh) ----
  int n0w = w*64, ln = lane&15, hi = lane>>4;
  f32x4 accz[2][4], acch[2][4];
  #pragma unroll
  for (int i=0;i<2;i++)
    #pragma unroll
    for (int j=0;j<4;j++){ accz[i][j]=(f32x4){0,0,0,0}; acch[i][j]=(f32x4){0,0,0,0}; }
  for (int kt = 0; kt < 8; kt++){
    int k0 = kt*32;
    bf16x8 aF[2], bF[4];
    aF[0] = ldsA(sA, 0, lane, k0);
    aF[1] = ldsA(sA, 16, lane, k0);
    #pragma unroll
    for (int i=0;i<4;i++) bF[i] = ldgB(Wz, 768, 512, n0w + i*16, lane, k0);
    #pragma unroll
    for (int mi=0;mi<2;mi++)
      #pragma unroll
      for (int ni=0;ni<4;ni++) accz[mi][ni] = mfma16(aF[mi], bF[ni], accz[mi][ni]);
  }
  for (int kt = 0; kt < 8; kt++){
    int k0 = kt*32;
    bf16x8 aF[2], bF[4];
    aF[0] = ldsA(sB, 0, lane, k0);
    aF[1] = ldsA(sB, 16, lane, k0);
    #pragma unroll
    for (int i=0;i<4;i++) bF[i] = ldgB(Wh, 768, 512, n0w + i*16, lane, k0);
    #pragma unroll
    for (int mi=0;mi<2;mi++)
      #pragma unroll
      for (int ni=0;ni<4;ni++) acch[mi][ni] = mfma16(aF[mi], bF[ni], acch[mi][ni]);
  }
  __syncthreads();   // all waves done reading sA/sB

  // ---- epilogue: z/r/h GRU update, write h_new (global + sB) ----
  #pragma unroll
  for (int mi=0;mi<2;mi++)
    #pragma unroll
    for (int ni=0;ni<4;ni++){
      int col = n0w + ni*16 + ln;
      #pragma unroll
      for (int r=0;r<4;r++){
        int rowl = mi*16 + hi*4 + r;
        int rowg = base + rowl;
        int c = sC[rowl];
        float shv = bf2f(sA[sidx(rowl, col)]);
        float z  = sigm(g_tz[c*256+col] + accz[mi][ni][r]);
        float ph = tanh_f(g_th[c*256+col] + acch[mi][ni][r]);
        float hn = (1.0f - z)*shv + z*ph;
        if (rowg == 0) hn = 0.f;
        ushort_t hb = f2bf(hn);
        hun[(size_t)rowg*HU_LD + col] = hb;
        sB[sidx(rowl,col)] = hb;
      }
    }
  if (last) return;  // uniform: no uh needed after final iteration
  __syncthreads();

  // ---- Uh GEMM: h_new x Ur^T ----
  f32x4 accu[2][4];
  #pragma unroll
  for (int i=0;i<2;i++)
    #pragma unroll
    for (int j=0;j<4;j++) accu[i][j]=(f32x4){0,0,0,0};
  for (int kt = 0; kt < 8; kt++){
    int k0 = kt*32;
    bf16x8 aF[2], bF[4];
    aF[0] = ldsA(sB, 0, lane, k0);
    aF[1] = ldsA(sB, 16, lane, k0);
    #pragma unroll
    for (int i=0;i<4;i++) bF[i] = ldgB(Ur, 256, 0, n0w + i*16, lane, k0);
    #pragma unroll
    for (int mi=0;mi<2;mi++)
      #pragma unroll
      for (int ni=0;ni<4;ni++) accu[mi][ni] = mfma16(aF[mi], bF[ni], accu[mi][ni]);
  }
  #pragma unroll
  for (int mi=0;mi<2;mi++)
    #pragma unroll
    for (int ni=0;ni<4;ni++){
      int col = n0w + ni*16 + ln;
      #pragma unroll
      for (int r=0;r<4;r++){
        int rowg = base + mi*16 + hi*4 + r;
        hun[(size_t)rowg*HU_LD + 256 + col] = f2bf(accu[mi][ni][r]);
      }
    }
}

// ---------------- K5: tail (agraph gather + O1 relu + O2) ------------------
__global__ __launch_bounds__(256) void k_tail(const int* agraph, const int* fnode,
                                              void* out_v, int rd){
  __shared__ __align__(16) ushort_t sT[64*256];
  const ushort_t* __restrict__ hup = rd ? g_hu1 : g_hu0;
  const ushort_t* O1  = c_w + OFF_O1;
  const ushort_t* O2  = c_w + OFF_O2;
  const ushort_t* O2b = c_w + OFF_O2b;
  int base = blockIdx.x*64, t = threadIdx.x;
  int w = t>>6, lane = t&63;
  for (int i = 0; i < 16; i++){
    int rowl = w*16 + i;
    int a = base + rowl;
    float a0=0,a1=0,a2=0,a3=0;
    if (a < AA){
      #pragma unroll
      for (int k = 0; k < KA; k++){
        int j = agraph[a*KA + k];
        ushort4 hv = *(const ushort4*)(hup + (size_t)j*HU_LD + lane*4);
        a0+=bf2f(hv.x); a1+=bf2f(hv.y); a2+=bf2f(hv.z); a3+=bf2f(hv.w);
      }
    }
    *(ushort4*)(sT + sidx(rowl, lane*4)) = make_ushort4(f2bf(a0),f2bf(a1),f2bf(a2),f2bf(a3));
  }
  __syncthreads();
  int n0w = w*64, ln = lane&15, hi = lane>>4;
  f32x4 acc[4][4];
  #pragma unroll
  for (int i=0;i<4;i++)
    #pragma unroll
    for (int j=0;j<4;j++) acc[i][j]=(f32x4){0,0,0,0};
  for (int kt = 0; kt < 8; kt++){
    int k0 = kt*32;
    bf16x8 aF[4], bF[4];
    #pragma unroll
    for (int i=0;i<4;i++) aF[i] = ldsA(sT, i*16, lane, k0);
    #pragma unroll
    for (int i=0;i<4;i++) bF[i] = ldgB(O1, 512, 256, n0w + i*16, lane, k0);
    #pragma unroll
    for (int mi=0;mi<4;mi++)
      #pragma unroll
      for (int ni=0;ni<4;ni++) acc[mi][ni] = mfma16(aF[mi], bF[ni], acc[mi][ni]);
  }
  __syncthreads();
  #pragma unroll
  for (int mi=0;mi<4;mi++)
    #pragma unroll
    for (int ni=0;ni<4;ni++){
      int col = n0w + ni*16 + ln;
      #pragma unroll
      for (int r=0;r<4;r++){
        int rowl = mi*16 + hi*4 + r;
        int a = base + rowl;
        int tt = (a < AA) ? fnode[a] : 0;
        float pre = g_to1[tt*256+col] + acc[mi][ni][r];
        sT[sidx(rowl,col)] = f2bf(fmaxf(pre, 0.f));
      }
    }
  __syncthreads();
  f32x4 acco[4][4];
  #pragma unroll
  for (int i=0;i<4;i++)
    #pragma unroll
    for (int j=0;j<4;j++) acco[i][j]=(f32x4){0,0,0,0};
  for (int kt = 0; kt < 8; kt++){
    int k0 = kt*32;
    bf16x8 aF[4], bF[4];
    #pragma unroll
    for (int i=0;i<4;i++) aF[i] = ldsA(sT, i*16, lane, k0);
    #pragma unroll
    for (int i=0;i<4;i++) bF[i] = ldgB(O2, 256, 0, n0w + i*16, lane, k0);
    #pragma unroll
    for (int mi=0;mi<4;mi++)
      #pragma unroll
      for (int ni=0;ni<4;ni++) acco[mi][ni] = mfma16(aF[mi], bF[ni], acco[mi][ni]);
  }
  int isf32 = g_isf32;
  #pragma unroll
  for (int mi=0;mi<4;mi++)
    #pragma unroll
    for (int ni=0;ni<4;ni++){
      int col = n0w + ni*16 + ln;
      float bias = bf2f(O2b[col]);
      #pragma unroll
      for (int r=0;r<4;r++){
        int rowg = base + mi*16 + hi*4 + r;
        if (rowg < AA){
          float v = acco[mi][ni][r] + bias;
          if (isf32) ((float*)out_v)[rowg*256 + col] = v;
          else       ((ushort_t*)out_v)[rowg*256 + col] = f2bf(v);
        }
      }
    }
}

// ---------------- launch ----------------------------------------------------
extern "C" void kernel_launch(void* const* d_in, const int* in_sizes, int n_in,
                              void* d_out, int out_size, void* d_ws, size_t ws_size,
                              hipStream_t stream) {
  const int* fnode = (const int*)d_in[13];
  const int* fsrc  = (const int*)d_in[14];
  const int* fbond = (const int*)d_in[15];
  const int* agraph = (const int*)d_in[16];
  const int* bgraph = (const int*)d_in[17];
  // depth is fixed at 4 by the problem setup

  k_detect<<<1, 256, 0, stream>>>((const ushort_t*)d_in[0]);
  k_convert<<<(W_TOTAL + 255)/256, 256, 0, stream>>>(
      d_in[0], d_in[1], d_in[2], d_in[3], d_in[4], d_in[5], d_in[6],
      d_in[7], d_in[8], d_in[9], d_in[10], d_in[11], d_in[12]);
  k_tables<<<3*NC + NATOM, 256, 0, stream>>>();
  k_cidx<<<(MM + 255)/256, 256, 0, stream>>>(fnode, fsrc, fbond);
  k_iter0<<<MM/64, 256, 0, stream>>>();                 // h0,uh0 -> buf0
  k_fused<<<MM/32, 256, 0, stream>>>(bgraph, 0, 0);     // it1: buf0 -> buf1
  k_fused<<<MM/32, 256, 0, stream>>>(bgraph, 1, 0);     // it2: buf1 -> buf0
  k_fused<<<MM/32, 256, 0, stream>>>(bgraph, 0, 1);     // it3: buf0 -> buf1 (no uh)
  k_tail<<<(AA + 63)/64, 256, 0, stream>>>(agraph, fnode, (void*)d_out, 1);
}